// Round 14
// baseline (1383.026 us; speedup 1.0000x reference)
//
#include <hip/hip_runtime.h>
#include <hip/hip_fp16.h>
#include <math.h>

#define N_NODES 100000
#define N_EDGES 1600000
#define DIM     128
#define NLAYER  5
#define NGRAPH  128
#define NTASK   10
#define NBOND   4
#define BN_EPS  1e-5f

// ---------------------------------------------------------------- scan (CSR offsets) + deg
__global__ __launch_bounds__(256) void scan1_kernel(
    const int* __restrict__ cnt, int* __restrict__ excl, int* __restrict__ bsum,
    const int* __restrict__ cnt_row, float* __restrict__ deg, float* __restrict__ dinv) {
  __shared__ int s[256];
  int t = threadIdx.x;
  int i = blockIdx.x * 256 + t;
  // fused degree computation (was deg_kernel)
  if (i < N_NODES) {
    float d = (float)cnt_row[i] + 1.0f;
    deg[i] = d;
    dinv[i] = rsqrtf(d);
  }
  int v = (i < N_NODES) ? cnt[i] : 0;
  s[t] = v;
  __syncthreads();
  for (int off = 1; off < 256; off <<= 1) {
    int add = (t >= off) ? s[t - off] : 0;
    __syncthreads();
    s[t] += add;
    __syncthreads();
  }
  if (i < N_NODES) excl[i] = s[t] - v;   // exclusive within block
  if (t == 255) bsum[blockIdx.x] = s[255];
}

__global__ __launch_bounds__(512) void scan2_kernel(
    const int* __restrict__ bsum, int* __restrict__ bexcl, int nb) {
  __shared__ int s[512];
  int t = threadIdx.x;
  int v = (t < nb) ? bsum[t] : 0;
  s[t] = v;
  __syncthreads();
  for (int off = 1; off < 512; off <<= 1) {
    int add = (t >= off) ? s[t - off] : 0;
    __syncthreads();
    s[t] += add;
    __syncthreads();
  }
  if (t < nb) bexcl[t] = s[t] - v;
}

__global__ __launch_bounds__(256) void scan3_kernel(
    int* __restrict__ excl, const int* __restrict__ bexcl) {
  int i = blockIdx.x * 256 + threadIdx.x;
  if (i < N_NODES) excl[i] += bexcl[blockIdx.x];
  if (i == 0) excl[N_NODES] = N_EDGES;
}

// ---------------------------------------------------------------- CSR scatter
// Separate src_pack/enorm arrays (R12 A/B: packed int2 costs ~18us/layer in agg).
__global__ __launch_bounds__(256) void scatter_kernel(
    const int* __restrict__ row, const int* __restrict__ col,
    const int* __restrict__ attr, const int* __restrict__ csr_off,
    int* __restrict__ pos, const float* __restrict__ dinv,
    int* __restrict__ src_pack, float* __restrict__ enorm) {
  int e = blockIdx.x * blockDim.x + threadIdx.x;
  int stride = gridDim.x * blockDim.x;
  for (; e < N_EDGES; e += stride) {
    int d = col[e];
    int s = row[e];
    int p = csr_off[d] + atomicAdd(&pos[d], 1);
    src_pack[p] = s | (attr[e] << 20);         // src < 2^20, attr < 4
    enorm[p] = dinv[s] * dinv[d];
  }
}

// ---------------------------------------------------------------- BN coeff helper
// Exact float-op replica of the original bnfin computation (bit-identical).
__device__ __forceinline__ void bn_coeff(float s, float q, float g, float b,
                                         float& sc, float& sh) {
  const float invN = 1.0f / (float)N_NODES;
  float mu = s * invN;
  float ex2 = q * invN;
  float var = ex2 - mu * mu;
  float inv = rsqrtf(var + BN_EPS);
  sc = g * inv;
  sh = fmaf(-mu, sc, b);
}

__device__ __forceinline__ void bn_coeff4(float4 s, float4 q, float4 g, float4 b,
                                          float4& sc, float4& sh) {
  bn_coeff(s.x, q.x, g.x, b.x, sc.x, sh.x);
  bn_coeff(s.y, q.y, g.y, b.y, sc.y, sh.y);
  bn_coeff(s.z, q.z, g.z, b.z, sc.z, sh.z);
  bn_coeff(s.w, q.w, g.w, b.w, sc.w, sh.w);
}

// ---------------------------------------------------------------- GEMM body
// R8/R10 structure: 4-phase async-prefetch, 512 threads, 32 KB LDS, 4x8 tile,
// ~104 live regs (fits the 128-VGPR 4-waves/SIMD tier). hx written as FP16
// (halves agg's byte-service-bound gather). BN coeffs (USEACT) computed inline
// from the previous layer's partials. FMA order: p asc x k4 asc x kk asc,
// init=bias -> bit-identical across rounds.
#define GBM 128
template<int USEACT>
__device__ __forceinline__ void gemm_body(
    const float* __restrict__ hin, const float* __restrict__ W,
    const float* __restrict__ bias, const float* __restrict__ bnprev,
    const float* __restrict__ gammaL, const float* __restrict__ betaL,
    uint2* __restrict__ hxh, float4* hs, float4* Ws, int bid) {
  int t = threadIdx.x;                  // 0..511
  int cg = t & 15;                      // column group: cols 4cg.. and 64+4cg..
  int rg = t >> 4;                      // row group 0..31: rows rg+32i
  int cr = rg & 3;                      // hs swizzle const ((rg+32i)&3 == rg&3)
  int slot = t & 7;                     // staging f4 slot (constant per thread)
  int srow = t >> 3;                    // staging rows srow, srow+64
  int sswz = slot ^ (srow & 3);         // swizzled slot ((srow+64)&3 == srow&3)
  int r0 = bid * GBM;
  if (r0 > N_NODES - GBM) r0 = N_NODES - GBM;   // tail overlap (benign dup stores)

  const float4* hg = (const float4*)hin;
  const float4* wg = (const float4*)W;
  const float4* bs4 = (const float4*)bnprev;   // [0..31]=sum, [32..63]=sumsq
  const float4* g4 = (const float4*)gammaL;
  const float4* b4 = (const float4*)betaL;

  float acc0[4][4], acc1[4][4];
  {
    float b0[4], b1[4];
#pragma unroll
    for (int j = 0; j < 4; j++) {
      b0[j] = bias[4 * cg + j];
      b1[j] = bias[64 + 4 * cg + j];
    }
#pragma unroll
    for (int i = 0; i < 4; i++)
#pragma unroll
      for (int j = 0; j < 4; j++) { acc0[i][j] = b0[j]; acc1[i][j] = b1[j]; }
  }

  // ---- prefetch phase 0 into registers (+ BN coeffs for this thread's slot)
  float4 psc, psh;
  if (USEACT) {
    bn_coeff4(bs4[slot], bs4[32 + slot], g4[slot], b4[slot], psc, psh);
  }
  float4 ph0 = hg[(size_t)(r0 + srow) * 32 + slot];
  float4 ph1 = hg[(size_t)(r0 + srow + 64) * 32 + slot];
  float4 pw0 = wg[t];
  float4 pw1 = wg[512 + t];

#pragma unroll 1
  for (int p = 0; p < 4; ++p) {
    // ---- write staged registers to LDS (act fused)
    float4 v0 = ph0, v1 = ph1;
    if (USEACT) {
      v0.x = fmaxf(fmaf(v0.x, psc.x, psh.x), 0.f);
      v0.y = fmaxf(fmaf(v0.y, psc.y, psh.y), 0.f);
      v0.z = fmaxf(fmaf(v0.z, psc.z, psh.z), 0.f);
      v0.w = fmaxf(fmaf(v0.w, psc.w, psh.w), 0.f);
      v1.x = fmaxf(fmaf(v1.x, psc.x, psh.x), 0.f);
      v1.y = fmaxf(fmaf(v1.y, psc.y, psh.y), 0.f);
      v1.z = fmaxf(fmaf(v1.z, psc.z, psh.z), 0.f);
      v1.w = fmaxf(fmaf(v1.w, psc.w, psh.w), 0.f);
    }
    hs[srow * 8 + sswz] = v0;
    hs[(srow + 64) * 8 + sswz] = v1;
    Ws[t] = pw0;
    Ws[512 + t] = pw1;
    __syncthreads();
    // ---- issue next phase's global loads (latency hides under compute)
    if (p < 3) {
      if (USEACT) {
        bn_coeff4(bs4[(p + 1) * 8 + slot], bs4[32 + (p + 1) * 8 + slot],
                  g4[(p + 1) * 8 + slot], b4[(p + 1) * 8 + slot], psc, psh);
      }
      ph0 = hg[(size_t)(r0 + srow) * 32 + (p + 1) * 8 + slot];
      ph1 = hg[(size_t)(r0 + srow + 64) * 32 + (p + 1) * 8 + slot];
      pw0 = wg[(p + 1) * 1024 + t];
      pw1 = wg[(p + 1) * 1024 + 512 + t];
    }
    // ---- compute phase p (k = 32p .. 32p+31)
#pragma unroll 1
    for (int k4 = 0; k4 < 8; k4++) {
      float4 w0[4], w1[4];
#pragma unroll
      for (int kk = 0; kk < 4; kk++) {
        w0[kk] = Ws[(k4 * 4 + kk) * 32 + cg];
        w1[kk] = Ws[(k4 * 4 + kk) * 32 + 16 + cg];
      }
      int soff = k4 ^ cr;
#pragma unroll
      for (int i = 0; i < 4; i++) {
        float4 hf = hs[(rg + 32 * i) * 8 + soff];
#pragma unroll
        for (int kk = 0; kk < 4; kk++) {
          float hv = ((const float*)&hf)[kk];
          acc0[i][0] = fmaf(hv, w0[kk].x, acc0[i][0]);
          acc0[i][1] = fmaf(hv, w0[kk].y, acc0[i][1]);
          acc0[i][2] = fmaf(hv, w0[kk].z, acc0[i][2]);
          acc0[i][3] = fmaf(hv, w0[kk].w, acc0[i][3]);
          acc1[i][0] = fmaf(hv, w1[kk].x, acc1[i][0]);
          acc1[i][1] = fmaf(hv, w1[kk].y, acc1[i][1]);
          acc1[i][2] = fmaf(hv, w1[kk].z, acc1[i][2]);
          acc1[i][3] = fmaf(hv, w1[kk].w, acc1[i][3]);
        }
      }
    }
    __syncthreads();   // all reads of this phase done before next overwrite
  }
  // ---- store as FP16 (4 halves = uint2 per column-quad)
#pragma unroll
  for (int i = 0; i < 4; i++) {
    int grow = r0 + rg + 32 * i;
    __half2 a01 = __floats2half2_rn(acc0[i][0], acc0[i][1]);
    __half2 a23 = __floats2half2_rn(acc0[i][2], acc0[i][3]);
    __half2 c01 = __floats2half2_rn(acc1[i][0], acc1[i][1]);
    __half2 c23 = __floats2half2_rn(acc1[i][2], acc1[i][3]);
    uint2 u0, u1;
    u0.x = __builtin_bit_cast(unsigned int, a01);
    u0.y = __builtin_bit_cast(unsigned int, a23);
    u1.x = __builtin_bit_cast(unsigned int, c01);
    u1.y = __builtin_bit_cast(unsigned int, c23);
    hxh[(size_t)grow * 32 + cg] = u0;
    hxh[(size_t)grow * 32 + 16 + cg] = u1;
  }
}

// ---------------------------------------------------------------- gemm layers 1-4
__global__ __launch_bounds__(512, 4) void gemm_kernel(
    const float* __restrict__ hin, const float* __restrict__ W,
    const float* __restrict__ bias, const float* __restrict__ bnprev,
    const float* __restrict__ gammaL, const float* __restrict__ betaL,
    uint2* __restrict__ hxh, float* __restrict__ bnzero) {
  __shared__ float4 hs[128 * 8];
  __shared__ float4 Ws[32 * 32];
  if (blockIdx.x == 0 && threadIdx.x < 256) bnzero[threadIdx.x] = 0.0f;
  gemm_body<1>(hin, W, bias, bnprev, gammaL, betaL, hxh, hs, Ws, blockIdx.x);
}

// ---------------------------------------------------------------- gemm layer 0 + edge histograms (fused)
// ~Neutral vs separate (R13 A/B) but one dispatch fewer; kept.
__global__ __launch_bounds__(512, 4) void gemm0_hist_kernel(
    const float* __restrict__ x, const float* __restrict__ W,
    const float* __restrict__ bias, uint2* __restrict__ hxh,
    float* __restrict__ bnzero,
    const int* __restrict__ row, const int* __restrict__ col,
    int* __restrict__ cnt_row, int* __restrict__ cnt_col, int gblocks) {
  __shared__ float4 hs[128 * 8];
  __shared__ float4 Ws[32 * 32];
  int t = threadIdx.x;
  if ((int)blockIdx.x >= gblocks) {     // histogram branch (block-uniform)
    int i = ((int)blockIdx.x - gblocks) * 512 + t;
    int stride = ((int)gridDim.x - gblocks) * 512;
    for (; i < N_EDGES; i += stride) {
      atomicAdd(&cnt_row[row[i]], 1);
      atomicAdd(&cnt_col[col[i]], 1);
    }
    return;
  }
  if (blockIdx.x == 0 && t < 256) bnzero[t] = 0.0f;
  gemm_body<0>(x, W, bias, nullptr, nullptr, nullptr, hxh, hs, Ws, blockIdx.x);
}

// ---------------------------------------------------------------- edge aggregation
// R14: 8-deep gather pipeline per half-wave (16 in flight/wave). Rationale:
// at fp32 rows (512B) deepening 2->4 was neutral (service-rate-bound); the
// fp16 rows (256B) halved per-request bytes and agg landed at ~105us, not the
// ~81 a pure service-rate model predicts -> partially latency-bound again.
// Doubling requests in flight restores the byte depth. In-flight state kept
// to sp[8]+nr[8]+u[8] (~40 regs, bondS read lazily) to stay in the <=64-VGPR
// occupancy tier. Accumulation order (ascending e per half) unchanged ->
// bit-identical results.
__global__ __launch_bounds__(256) void agg_kernel(
    const uint2* __restrict__ hxh, const int* __restrict__ csr_off,
    const int* __restrict__ src_pack, const float* __restrict__ enorm,
    const float* __restrict__ bond, const float* __restrict__ root,
    const float* __restrict__ deg, float* __restrict__ h2,
    float* __restrict__ bnbuf) {
  __shared__ float4 bondS[NBOND * 32];
  __shared__ float4 rootS[32];
  __shared__ float sbn[256];
  int t = threadIdx.x;
  if (t < NBOND * 32) bondS[t] = ((const float4*)bond)[t];
  if (t < 32) rootS[t] = ((const float4*)root)[t];
  sbn[t] = 0.0f;
  __syncthreads();

  int lane = t & 63;
  int laneq = lane & 31;   // feature quad owner
  int half = lane >> 5;    // which edge stream of the pair
  int wid = t >> 6;
  int gw = blockIdx.x * 4 + wid;
  int nw = gridDim.x * 4;
  float4* h24 = (float4*)h2;

  float s0 = 0.f, s1 = 0.f, s2 = 0.f, s3 = 0.f;
  float q0 = 0.f, q1 = 0.f, q2 = 0.f, q3 = 0.f;
  for (int n = gw; n < N_NODES; n += nw) {
    int e0 = csr_off[n], e1 = csr_off[n + 1];
    float a0 = 0.f, a1 = 0.f, a2 = 0.f, a3 = 0.f;
    int e = e0 + half;
    // 8-deep: edges e, e+2, ..., e+14 for this half-wave
    for (; e + 14 < e1; e += 16) {
      int sp[8];
      float nr[8];
      uint2 u[8];
#pragma unroll
      for (int j = 0; j < 8; j++) {
        sp[j] = src_pack[e + 2 * j];
        nr[j] = enorm[e + 2 * j];
      }
#pragma unroll
      for (int j = 0; j < 8; j++)
        u[j] = hxh[(size_t)(sp[j] & 0xFFFFF) * 32 + laneq];
#pragma unroll
      for (int j = 0; j < 8; j++) {
        float4 bb = bondS[(sp[j] >> 20) * 32 + laneq];
        float2 va = __half22float2(__builtin_bit_cast(__half2, u[j].x));
        float2 vb = __half22float2(__builtin_bit_cast(__half2, u[j].y));
        a0 = fmaf(nr[j], fmaxf(va.x + bb.x, 0.f), a0);
        a1 = fmaf(nr[j], fmaxf(va.y + bb.y, 0.f), a1);
        a2 = fmaf(nr[j], fmaxf(vb.x + bb.z, 0.f), a2);
        a3 = fmaf(nr[j], fmaxf(vb.y + bb.w, 0.f), a3);
      }
    }
    for (; e < e1; e += 2) {
      int sp = src_pack[e];
      float nrm = enorm[e];
      uint2 u = hxh[(size_t)(sp & 0xFFFFF) * 32 + laneq];
      float4 eb = bondS[(sp >> 20) * 32 + laneq];
      float2 va = __half22float2(__builtin_bit_cast(__half2, u.x));
      float2 vb = __half22float2(__builtin_bit_cast(__half2, u.y));
      a0 = fmaf(nrm, fmaxf(va.x + eb.x, 0.f), a0);
      a1 = fmaf(nrm, fmaxf(va.y + eb.y, 0.f), a1);
      a2 = fmaf(nrm, fmaxf(vb.x + eb.z, 0.f), a2);
      a3 = fmaf(nrm, fmaxf(vb.y + eb.w, 0.f), a3);
    }
    // combine the two halves (lane l and l^32 hold partials for same features)
    a0 += __shfl_xor(a0, 32, 64);
    a1 += __shfl_xor(a1, 32, 64);
    a2 += __shfl_xor(a2, 32, 64);
    a3 += __shfl_xor(a3, 32, 64);
    if (half == 0) {
      float inv = 1.0f / deg[n];
      uint2 u = hxh[(size_t)n * 32 + laneq];
      float2 va = __half22float2(__builtin_bit_cast(__half2, u.x));
      float2 vb = __half22float2(__builtin_bit_cast(__half2, u.y));
      float4 r = rootS[laneq];
      a0 += fmaxf(va.x + r.x, 0.f) * inv;
      a1 += fmaxf(va.y + r.y, 0.f) * inv;
      a2 += fmaxf(vb.x + r.z, 0.f) * inv;
      a3 += fmaxf(vb.y + r.w, 0.f) * inv;
      float4 o;
      o.x = a0; o.y = a1; o.z = a2; o.w = a3;
      h24[(size_t)n * 32 + laneq] = o;
      s0 += a0; s1 += a1; s2 += a2; s3 += a3;
      q0 += a0 * a0; q1 += a1 * a1; q2 += a2 * a2; q3 += a3 * a3;
    }
  }
  // block-level BN reduction: LDS atomics, then one global atomic per feature
  if (half == 0) {
    int f = 4 * laneq;
    atomicAdd(&sbn[f + 0], s0);
    atomicAdd(&sbn[f + 1], s1);
    atomicAdd(&sbn[f + 2], s2);
    atomicAdd(&sbn[f + 3], s3);
    atomicAdd(&sbn[128 + f + 0], q0);
    atomicAdd(&sbn[128 + f + 1], q1);
    atomicAdd(&sbn[128 + f + 2], q2);
    atomicAdd(&sbn[128 + f + 3], q3);
  }
  __syncthreads();
  atomicAdd(&bnbuf[t], sbn[t]);
}

// ---------------------------------------------------------------- pooling (batch is sorted)
// BN coefficients for the last layer computed inline.
__global__ __launch_bounds__(256) void pool_kernel(
    const float* __restrict__ h2, const int* __restrict__ batch,
    const float* __restrict__ bnlast, const float* __restrict__ gammaL,
    const float* __restrict__ betaL,
    float* __restrict__ pool, float* __restrict__ pcnt) {
  int t = threadIdx.x;
  int lane = t & 63;
  int wid = t >> 6;
  int gw = blockIdx.x * 4 + wid;
  int nw = gridDim.x * 4;
  int chunk = (N_NODES + nw - 1) / nw;
  int n0 = gw * chunk;
  int n1 = min(n0 + chunk, N_NODES);
  if (n0 >= N_NODES) return;
  const float2* h22 = (const float2*)h2;
  int f0 = 2 * lane, f1 = f0 + 1;
  float sc0, sh0, sc1, sh1;
  bn_coeff(bnlast[f0], bnlast[128 + f0], gammaL[f0], betaL[f0], sc0, sh0);
  bn_coeff(bnlast[f1], bnlast[128 + f1], gammaL[f1], betaL[f1], sc1, sh1);
  int curg = batch[n0];
  float a0 = 0.f, a1 = 0.f, c = 0.f;
  for (int n = n0; n < n1; n++) {
    int g = batch[n];
    if (g != curg) {
      atomicAdd(&pool[curg * DIM + f0], a0);
      atomicAdd(&pool[curg * DIM + f1], a1);
      if (lane == 0) atomicAdd(&pcnt[curg], c);
      a0 = a1 = c = 0.f;
      curg = g;
    }
    float2 v = h22[(size_t)n * 64 + lane];
    a0 += fmaxf(fmaf(v.x, sc0, sh0), 0.f);
    a1 += fmaxf(fmaf(v.y, sc1, sh1), 0.f);
    c += 1.0f;
  }
  atomicAdd(&pool[curg * DIM + f0], a0);
  atomicAdd(&pool[curg * DIM + f1], a1);
  if (lane == 0) atomicAdd(&pcnt[curg], c);
}

// ---------------------------------------------------------------- output head
__global__ __launch_bounds__(256) void out_kernel(
    const float* __restrict__ pool, const float* __restrict__ pcnt,
    const float* __restrict__ Wout, const float* __restrict__ bout,
    float* __restrict__ out) {
  int idx = blockIdx.x * blockDim.x + threadIdx.x;
  if (idx >= NGRAPH * NTASK) return;
  int g = idx / NTASK, tt = idx % NTASK;
  float inv = 1.0f / fmaxf(pcnt[g], 1.0f);
  float acc = bout[tt];
  for (int d = 0; d < DIM; d++)
    acc = fmaf(pool[g * DIM + d] * inv, Wout[d * NTASK + tt], acc);
  out[idx] = acc;
}

// ----------------------------------------------------------------
extern "C" void kernel_launch(void* const* d_in, const int* in_sizes, int n_in,
                              void* d_out, int out_size, void* d_ws, size_t ws_size,
                              hipStream_t stream) {
  const float* x     = (const float*)d_in[0];
  const int*   eidx  = (const int*)d_in[1];
  const int*   row   = eidx;
  const int*   col   = eidx + N_EDGES;
  const int*   eattr = (const int*)d_in[2];
  const int*   batch = (const int*)d_in[3];
  const float* W     = (const float*)d_in[4];
  const float* b     = (const float*)d_in[5];
  const float* root  = (const float*)d_in[6];
  const float* bond  = (const float*)d_in[7];
  const float* gamma = (const float*)d_in[8];
  const float* beta  = (const float*)d_in[9];
  const float* Wout  = (const float*)d_in[10];
  const float* bout  = (const float*)d_in[11];
  float* out = (float*)d_out;

  // bump allocator over workspace
  char* w = (char*)d_ws;
  size_t off = 0;
  auto alloc = [&](size_t bytes) -> void* {
    void* p = w + off;
    off = (off + bytes + 511) & ~(size_t)511;
    return p;
  };
  // zero-init region (single memset): histograms, scatter positions, pool accumulators
  int*   cnt_row = (int*)alloc(N_NODES * 4);
  int*   cnt_col = (int*)alloc(N_NODES * 4);
  int*   pos     = (int*)alloc(N_NODES * 4);
  float* pool    = (float*)alloc(NGRAPH * DIM * 4);
  float* pcnt    = (float*)alloc(NGRAPH * 4);
  size_t zbytes  = off;
  // rest
  int*   csr     = (int*)alloc((N_NODES + 1) * 4);
  int*   bsum    = (int*)alloc(512 * 4);
  int*   bexcl   = (int*)alloc(512 * 4);
  float* deg     = (float*)alloc(N_NODES * 4);
  float* dinv    = (float*)alloc(N_NODES * 4);
  int*   spck    = (int*)alloc((size_t)N_EDGES * 4);
  float* enorm   = (float*)alloc((size_t)N_EDGES * 4);
  uint2* hxh     = (uint2*)alloc((size_t)N_NODES * DIM * 2);   // fp16 hx
  float* hA      = (float*)alloc((size_t)N_NODES * DIM * 4);
  float* hB      = (float*)alloc((size_t)N_NODES * DIM * 4);
  float* bnbufA  = (float*)alloc(256 * 4);
  float* bnbufB  = (float*)alloc(256 * 4);

  hipMemsetAsync(d_ws, 0, zbytes, stream);

  const int gblocks = (N_NODES + GBM - 1) / GBM;  // 782
  // fused: gemm layer 0 (independent of the graph) + edge histograms
  gemm0_hist_kernel<<<gblocks + 512, 512, 0, stream>>>(
      x, W, b, hxh, bnbufA, row, col, cnt_row, cnt_col, gblocks);

  const int nb = (N_NODES + 255) / 256;  // 391
  scan1_kernel<<<nb, 256, 0, stream>>>(cnt_col, csr, bsum, cnt_row, deg, dinv);
  scan2_kernel<<<1, 512, 0, stream>>>(bsum, bexcl, nb);
  scan3_kernel<<<nb, 256, 0, stream>>>(csr, bexcl);
  scatter_kernel<<<2048, 256, 0, stream>>>(row, col, eattr, csr, pos, dinv, spck, enorm);

  // layer 0 aggregation (gemm0 output already in hxh)
  agg_kernel<<<2048, 256, 0, stream>>>(
      hxh, csr, spck, enorm, bond, root, deg, hA, bnbufA);

  const float* hin = hA;
  for (int l = 1; l < NLAYER; l++) {
    float* h2      = (l % 2 == 0) ? hA : hB;
    float* bufcur  = (l % 2 == 0) ? bnbufA : bnbufB;   // this layer's partials
    float* bufprev = (l % 2 == 0) ? bnbufB : bnbufA;   // previous layer's
    gemm_kernel<<<gblocks, 512, 0, stream>>>(
        hin, W + (size_t)l * DIM * DIM, b + l * DIM,
        bufprev, gamma + (size_t)(l - 1) * DIM, beta + (size_t)(l - 1) * DIM,
        hxh, bufcur);
    agg_kernel<<<2048, 256, 0, stream>>>(
        hxh, csr, spck, enorm, bond + (size_t)l * NBOND * DIM, root + l * DIM,
        deg, h2, bufcur);
    hin = h2;
  }
  // layer 4 wrote bnbufA (4 % 2 == 0)
  pool_kernel<<<256, 256, 0, stream>>>(hin, batch, bnbufA,
                                       gamma + 4 * DIM, beta + 4 * DIM, pool, pcnt);
  out_kernel<<<5, 256, 0, stream>>>(pool, pcnt, Wout, bout, out);
}

// Round 15
// 1220.670 us; speedup vs baseline: 1.1330x; 1.1330x over previous
//
#include <hip/hip_runtime.h>
#include <hip/hip_fp16.h>
#include <math.h>

#define N_NODES 100000
#define N_EDGES 1600000
#define DIM     128
#define NLAYER  5
#define NGRAPH  128
#define NTASK   10
#define NBOND   4
#define BN_EPS  1e-5f

// ---------------------------------------------------------------- scan (CSR offsets) + deg
__global__ __launch_bounds__(256) void scan1_kernel(
    const int* __restrict__ cnt, int* __restrict__ excl, int* __restrict__ bsum,
    const int* __restrict__ cnt_row, float* __restrict__ deg, float* __restrict__ dinv) {
  __shared__ int s[256];
  int t = threadIdx.x;
  int i = blockIdx.x * 256 + t;
  // fused degree computation (was deg_kernel)
  if (i < N_NODES) {
    float d = (float)cnt_row[i] + 1.0f;
    deg[i] = d;
    dinv[i] = rsqrtf(d);
  }
  int v = (i < N_NODES) ? cnt[i] : 0;
  s[t] = v;
  __syncthreads();
  for (int off = 1; off < 256; off <<= 1) {
    int add = (t >= off) ? s[t - off] : 0;
    __syncthreads();
    s[t] += add;
    __syncthreads();
  }
  if (i < N_NODES) excl[i] = s[t] - v;   // exclusive within block
  if (t == 255) bsum[blockIdx.x] = s[255];
}

__global__ __launch_bounds__(512) void scan2_kernel(
    const int* __restrict__ bsum, int* __restrict__ bexcl, int nb) {
  __shared__ int s[512];
  int t = threadIdx.x;
  int v = (t < nb) ? bsum[t] : 0;
  s[t] = v;
  __syncthreads();
  for (int off = 1; off < 512; off <<= 1) {
    int add = (t >= off) ? s[t - off] : 0;
    __syncthreads();
    s[t] += add;
    __syncthreads();
  }
  if (t < nb) bexcl[t] = s[t] - v;
}

__global__ __launch_bounds__(256) void scan3_kernel(
    int* __restrict__ excl, const int* __restrict__ bexcl) {
  int i = blockIdx.x * 256 + threadIdx.x;
  if (i < N_NODES) excl[i] += bexcl[blockIdx.x];
  if (i == 0) excl[N_NODES] = N_EDGES;
}

// ---------------------------------------------------------------- CSR scatter
// Separate src_pack/enorm arrays (R12 A/B: packed int2 costs ~18us/layer in agg).
__global__ __launch_bounds__(256) void scatter_kernel(
    const int* __restrict__ row, const int* __restrict__ col,
    const int* __restrict__ attr, const int* __restrict__ csr_off,
    int* __restrict__ pos, const float* __restrict__ dinv,
    int* __restrict__ src_pack, float* __restrict__ enorm) {
  int e = blockIdx.x * blockDim.x + threadIdx.x;
  int stride = gridDim.x * blockDim.x;
  for (; e < N_EDGES; e += stride) {
    int d = col[e];
    int s = row[e];
    int p = csr_off[d] + atomicAdd(&pos[d], 1);
    src_pack[p] = s | (attr[e] << 20);         // src < 2^20, attr < 4
    enorm[p] = dinv[s] * dinv[d];
  }
}

// ---------------------------------------------------------------- BN coeff helper
// Exact float-op replica of the original bnfin computation (bit-identical).
__device__ __forceinline__ void bn_coeff(float s, float q, float g, float b,
                                         float& sc, float& sh) {
  const float invN = 1.0f / (float)N_NODES;
  float mu = s * invN;
  float ex2 = q * invN;
  float var = ex2 - mu * mu;
  float inv = rsqrtf(var + BN_EPS);
  sc = g * inv;
  sh = fmaf(-mu, sc, b);
}

__device__ __forceinline__ void bn_coeff4(float4 s, float4 q, float4 g, float4 b,
                                          float4& sc, float4& sh) {
  bn_coeff(s.x, q.x, g.x, b.x, sc.x, sh.x);
  bn_coeff(s.y, q.y, g.y, b.y, sc.y, sh.y);
  bn_coeff(s.z, q.z, g.z, b.z, sc.z, sh.z);
  bn_coeff(s.w, q.w, g.w, b.w, sc.w, sh.w);
}

// ---------------------------------------------------------------- GEMM body
// R8/R10 structure: 4-phase async-prefetch, 512 threads, 32 KB LDS, 4x8 tile,
// ~104 live regs (fits the 128-VGPR 4-waves/SIMD tier). hx written as FP16
// (halves agg's byte-service-bound gather). BN coeffs (USEACT) computed inline
// from the previous layer's partials. FMA order: p asc x k4 asc x kk asc,
// init=bias -> bit-identical across rounds.
#define GBM 128
template<int USEACT>
__device__ __forceinline__ void gemm_body(
    const float* __restrict__ hin, const float* __restrict__ W,
    const float* __restrict__ bias, const float* __restrict__ bnprev,
    const float* __restrict__ gammaL, const float* __restrict__ betaL,
    uint2* __restrict__ hxh, float4* hs, float4* Ws, int bid) {
  int t = threadIdx.x;                  // 0..511
  int cg = t & 15;                      // column group: cols 4cg.. and 64+4cg..
  int rg = t >> 4;                      // row group 0..31: rows rg+32i
  int cr = rg & 3;                      // hs swizzle const ((rg+32i)&3 == rg&3)
  int slot = t & 7;                     // staging f4 slot (constant per thread)
  int srow = t >> 3;                    // staging rows srow, srow+64
  int sswz = slot ^ (srow & 3);         // swizzled slot ((srow+64)&3 == srow&3)
  int r0 = bid * GBM;
  if (r0 > N_NODES - GBM) r0 = N_NODES - GBM;   // tail overlap (benign dup stores)

  const float4* hg = (const float4*)hin;
  const float4* wg = (const float4*)W;
  const float4* bs4 = (const float4*)bnprev;   // [0..31]=sum, [32..63]=sumsq
  const float4* g4 = (const float4*)gammaL;
  const float4* b4 = (const float4*)betaL;

  float acc0[4][4], acc1[4][4];
  {
    float b0[4], b1[4];
#pragma unroll
    for (int j = 0; j < 4; j++) {
      b0[j] = bias[4 * cg + j];
      b1[j] = bias[64 + 4 * cg + j];
    }
#pragma unroll
    for (int i = 0; i < 4; i++)
#pragma unroll
      for (int j = 0; j < 4; j++) { acc0[i][j] = b0[j]; acc1[i][j] = b1[j]; }
  }

  // ---- prefetch phase 0 into registers (+ BN coeffs for this thread's slot)
  float4 psc, psh;
  if (USEACT) {
    bn_coeff4(bs4[slot], bs4[32 + slot], g4[slot], b4[slot], psc, psh);
  }
  float4 ph0 = hg[(size_t)(r0 + srow) * 32 + slot];
  float4 ph1 = hg[(size_t)(r0 + srow + 64) * 32 + slot];
  float4 pw0 = wg[t];
  float4 pw1 = wg[512 + t];

#pragma unroll 1
  for (int p = 0; p < 4; ++p) {
    // ---- write staged registers to LDS (act fused)
    float4 v0 = ph0, v1 = ph1;
    if (USEACT) {
      v0.x = fmaxf(fmaf(v0.x, psc.x, psh.x), 0.f);
      v0.y = fmaxf(fmaf(v0.y, psc.y, psh.y), 0.f);
      v0.z = fmaxf(fmaf(v0.z, psc.z, psh.z), 0.f);
      v0.w = fmaxf(fmaf(v0.w, psc.w, psh.w), 0.f);
      v1.x = fmaxf(fmaf(v1.x, psc.x, psh.x), 0.f);
      v1.y = fmaxf(fmaf(v1.y, psc.y, psh.y), 0.f);
      v1.z = fmaxf(fmaf(v1.z, psc.z, psh.z), 0.f);
      v1.w = fmaxf(fmaf(v1.w, psc.w, psh.w), 0.f);
    }
    hs[srow * 8 + sswz] = v0;
    hs[(srow + 64) * 8 + sswz] = v1;
    Ws[t] = pw0;
    Ws[512 + t] = pw1;
    __syncthreads();
    // ---- issue next phase's global loads (latency hides under compute)
    if (p < 3) {
      if (USEACT) {
        bn_coeff4(bs4[(p + 1) * 8 + slot], bs4[32 + (p + 1) * 8 + slot],
                  g4[(p + 1) * 8 + slot], b4[(p + 1) * 8 + slot], psc, psh);
      }
      ph0 = hg[(size_t)(r0 + srow) * 32 + (p + 1) * 8 + slot];
      ph1 = hg[(size_t)(r0 + srow + 64) * 32 + (p + 1) * 8 + slot];
      pw0 = wg[(p + 1) * 1024 + t];
      pw1 = wg[(p + 1) * 1024 + 512 + t];
    }
    // ---- compute phase p (k = 32p .. 32p+31)
#pragma unroll 1
    for (int k4 = 0; k4 < 8; k4++) {
      float4 w0[4], w1[4];
#pragma unroll
      for (int kk = 0; kk < 4; kk++) {
        w0[kk] = Ws[(k4 * 4 + kk) * 32 + cg];
        w1[kk] = Ws[(k4 * 4 + kk) * 32 + 16 + cg];
      }
      int soff = k4 ^ cr;
#pragma unroll
      for (int i = 0; i < 4; i++) {
        float4 hf = hs[(rg + 32 * i) * 8 + soff];
#pragma unroll
        for (int kk = 0; kk < 4; kk++) {
          float hv = ((const float*)&hf)[kk];
          acc0[i][0] = fmaf(hv, w0[kk].x, acc0[i][0]);
          acc0[i][1] = fmaf(hv, w0[kk].y, acc0[i][1]);
          acc0[i][2] = fmaf(hv, w0[kk].z, acc0[i][2]);
          acc0[i][3] = fmaf(hv, w0[kk].w, acc0[i][3]);
          acc1[i][0] = fmaf(hv, w1[kk].x, acc1[i][0]);
          acc1[i][1] = fmaf(hv, w1[kk].y, acc1[i][1]);
          acc1[i][2] = fmaf(hv, w1[kk].z, acc1[i][2]);
          acc1[i][3] = fmaf(hv, w1[kk].w, acc1[i][3]);
        }
      }
    }
    __syncthreads();   // all reads of this phase done before next overwrite
  }
  // ---- store as FP16 (4 halves = uint2 per column-quad)
#pragma unroll
  for (int i = 0; i < 4; i++) {
    int grow = r0 + rg + 32 * i;
    __half2 a01 = __floats2half2_rn(acc0[i][0], acc0[i][1]);
    __half2 a23 = __floats2half2_rn(acc0[i][2], acc0[i][3]);
    __half2 c01 = __floats2half2_rn(acc1[i][0], acc1[i][1]);
    __half2 c23 = __floats2half2_rn(acc1[i][2], acc1[i][3]);
    uint2 u0, u1;
    u0.x = __builtin_bit_cast(unsigned int, a01);
    u0.y = __builtin_bit_cast(unsigned int, a23);
    u1.x = __builtin_bit_cast(unsigned int, c01);
    u1.y = __builtin_bit_cast(unsigned int, c23);
    hxh[(size_t)grow * 32 + cg] = u0;
    hxh[(size_t)grow * 32 + 16 + cg] = u1;
  }
}

// ---------------------------------------------------------------- gemm layers 1-4
__global__ __launch_bounds__(512, 4) void gemm_kernel(
    const float* __restrict__ hin, const float* __restrict__ W,
    const float* __restrict__ bias, const float* __restrict__ bnprev,
    const float* __restrict__ gammaL, const float* __restrict__ betaL,
    uint2* __restrict__ hxh, float* __restrict__ bnzero) {
  __shared__ float4 hs[128 * 8];
  __shared__ float4 Ws[32 * 32];
  if (blockIdx.x == 0 && threadIdx.x < 256) bnzero[threadIdx.x] = 0.0f;
  gemm_body<1>(hin, W, bias, bnprev, gammaL, betaL, hxh, hs, Ws, blockIdx.x);
}

// ---------------------------------------------------------------- gemm layer 0 + edge histograms (fused)
// ~Neutral vs separate (R13 A/B) but one dispatch fewer; kept.
__global__ __launch_bounds__(512, 4) void gemm0_hist_kernel(
    const float* __restrict__ x, const float* __restrict__ W,
    const float* __restrict__ bias, uint2* __restrict__ hxh,
    float* __restrict__ bnzero,
    const int* __restrict__ row, const int* __restrict__ col,
    int* __restrict__ cnt_row, int* __restrict__ cnt_col, int gblocks) {
  __shared__ float4 hs[128 * 8];
  __shared__ float4 Ws[32 * 32];
  int t = threadIdx.x;
  if ((int)blockIdx.x >= gblocks) {     // histogram branch (block-uniform)
    int i = ((int)blockIdx.x - gblocks) * 512 + t;
    int stride = ((int)gridDim.x - gblocks) * 512;
    for (; i < N_EDGES; i += stride) {
      atomicAdd(&cnt_row[row[i]], 1);
      atomicAdd(&cnt_col[col[i]], 1);
    }
    return;
  }
  if (blockIdx.x == 0 && t < 256) bnzero[t] = 0.0f;
  gemm_body<0>(x, W, bias, nullptr, nullptr, nullptr, hxh, hs, Ws, blockIdx.x);
}

// ---------------------------------------------------------------- edge aggregation
// R15: REVERTED to R13's 4-deep gather pipeline — the measured optimum.
// Depth bracket: 2->4 helped at fp32 rows (R1->R2), 4->8 hurt at fp16 rows
// (R13->R14, +32us/layer: sp[8]+nr[8]+u[8] live state broke the <=64-VGPR
// occupancy tier and lazy bondS reads serialized against the FMA chain).
// At depth 4 x 24 waves/CU the per-CU request queue is already full.
__global__ __launch_bounds__(256) void agg_kernel(
    const uint2* __restrict__ hxh, const int* __restrict__ csr_off,
    const int* __restrict__ src_pack, const float* __restrict__ enorm,
    const float* __restrict__ bond, const float* __restrict__ root,
    const float* __restrict__ deg, float* __restrict__ h2,
    float* __restrict__ bnbuf) {
  __shared__ float4 bondS[NBOND * 32];
  __shared__ float4 rootS[32];
  __shared__ float sbn[256];
  int t = threadIdx.x;
  if (t < NBOND * 32) bondS[t] = ((const float4*)bond)[t];
  if (t < 32) rootS[t] = ((const float4*)root)[t];
  sbn[t] = 0.0f;
  __syncthreads();

  int lane = t & 63;
  int laneq = lane & 31;   // feature quad owner
  int half = lane >> 5;    // which edge stream of the pair
  int wid = t >> 6;
  int gw = blockIdx.x * 4 + wid;
  int nw = gridDim.x * 4;
  float4* h24 = (float4*)h2;

  float s0 = 0.f, s1 = 0.f, s2 = 0.f, s3 = 0.f;
  float q0 = 0.f, q1 = 0.f, q2 = 0.f, q3 = 0.f;
  for (int n = gw; n < N_NODES; n += nw) {
    int e0 = csr_off[n], e1 = csr_off[n + 1];
    float a0 = 0.f, a1 = 0.f, a2 = 0.f, a3 = 0.f;
    int e = e0 + half;
    // unrolled 4x: edges e, e+2, e+4, e+6 for this half-wave
    for (; e + 6 < e1; e += 8) {
      int sp0 = src_pack[e];
      int sp1 = src_pack[e + 2];
      int sp2 = src_pack[e + 4];
      int sp3 = src_pack[e + 6];
      float nr0 = enorm[e];
      float nr1 = enorm[e + 2];
      float nr2 = enorm[e + 4];
      float nr3 = enorm[e + 6];
      uint2 u0 = hxh[(size_t)(sp0 & 0xFFFFF) * 32 + laneq];
      uint2 u1 = hxh[(size_t)(sp1 & 0xFFFFF) * 32 + laneq];
      uint2 u2 = hxh[(size_t)(sp2 & 0xFFFFF) * 32 + laneq];
      uint2 u3 = hxh[(size_t)(sp3 & 0xFFFFF) * 32 + laneq];
      float4 b0 = bondS[(sp0 >> 20) * 32 + laneq];
      float4 b1 = bondS[(sp1 >> 20) * 32 + laneq];
      float4 b2 = bondS[(sp2 >> 20) * 32 + laneq];
      float4 b3 = bondS[(sp3 >> 20) * 32 + laneq];
      float2 v0a = __half22float2(__builtin_bit_cast(__half2, u0.x));
      float2 v0b = __half22float2(__builtin_bit_cast(__half2, u0.y));
      float2 v1a = __half22float2(__builtin_bit_cast(__half2, u1.x));
      float2 v1b = __half22float2(__builtin_bit_cast(__half2, u1.y));
      float2 v2a = __half22float2(__builtin_bit_cast(__half2, u2.x));
      float2 v2b = __half22float2(__builtin_bit_cast(__half2, u2.y));
      float2 v3a = __half22float2(__builtin_bit_cast(__half2, u3.x));
      float2 v3b = __half22float2(__builtin_bit_cast(__half2, u3.y));
      a0 = fmaf(nr0, fmaxf(v0a.x + b0.x, 0.f), a0);
      a1 = fmaf(nr0, fmaxf(v0a.y + b0.y, 0.f), a1);
      a2 = fmaf(nr0, fmaxf(v0b.x + b0.z, 0.f), a2);
      a3 = fmaf(nr0, fmaxf(v0b.y + b0.w, 0.f), a3);
      a0 = fmaf(nr1, fmaxf(v1a.x + b1.x, 0.f), a0);
      a1 = fmaf(nr1, fmaxf(v1a.y + b1.y, 0.f), a1);
      a2 = fmaf(nr1, fmaxf(v1b.x + b1.z, 0.f), a2);
      a3 = fmaf(nr1, fmaxf(v1b.y + b1.w, 0.f), a3);
      a0 = fmaf(nr2, fmaxf(v2a.x + b2.x, 0.f), a0);
      a1 = fmaf(nr2, fmaxf(v2a.y + b2.y, 0.f), a1);
      a2 = fmaf(nr2, fmaxf(v2b.x + b2.z, 0.f), a2);
      a3 = fmaf(nr2, fmaxf(v2b.y + b2.w, 0.f), a3);
      a0 = fmaf(nr3, fmaxf(v3a.x + b3.x, 0.f), a0);
      a1 = fmaf(nr3, fmaxf(v3a.y + b3.y, 0.f), a1);
      a2 = fmaf(nr3, fmaxf(v3b.x + b3.z, 0.f), a2);
      a3 = fmaf(nr3, fmaxf(v3b.y + b3.w, 0.f), a3);
    }
    for (; e < e1; e += 2) {
      int sp = src_pack[e];
      float nrm = enorm[e];
      uint2 u = hxh[(size_t)(sp & 0xFFFFF) * 32 + laneq];
      float4 eb = bondS[(sp >> 20) * 32 + laneq];
      float2 va = __half22float2(__builtin_bit_cast(__half2, u.x));
      float2 vb = __half22float2(__builtin_bit_cast(__half2, u.y));
      a0 = fmaf(nrm, fmaxf(va.x + eb.x, 0.f), a0);
      a1 = fmaf(nrm, fmaxf(va.y + eb.y, 0.f), a1);
      a2 = fmaf(nrm, fmaxf(vb.x + eb.z, 0.f), a2);
      a3 = fmaf(nrm, fmaxf(vb.y + eb.w, 0.f), a3);
    }
    // combine the two halves (lane l and l^32 hold partials for same features)
    a0 += __shfl_xor(a0, 32, 64);
    a1 += __shfl_xor(a1, 32, 64);
    a2 += __shfl_xor(a2, 32, 64);
    a3 += __shfl_xor(a3, 32, 64);
    if (half == 0) {
      float inv = 1.0f / deg[n];
      uint2 u = hxh[(size_t)n * 32 + laneq];
      float2 va = __half22float2(__builtin_bit_cast(__half2, u.x));
      float2 vb = __half22float2(__builtin_bit_cast(__half2, u.y));
      float4 r = rootS[laneq];
      a0 += fmaxf(va.x + r.x, 0.f) * inv;
      a1 += fmaxf(va.y + r.y, 0.f) * inv;
      a2 += fmaxf(vb.x + r.z, 0.f) * inv;
      a3 += fmaxf(vb.y + r.w, 0.f) * inv;
      float4 o;
      o.x = a0; o.y = a1; o.z = a2; o.w = a3;
      h24[(size_t)n * 32 + laneq] = o;
      s0 += a0; s1 += a1; s2 += a2; s3 += a3;
      q0 += a0 * a0; q1 += a1 * a1; q2 += a2 * a2; q3 += a3 * a3;
    }
  }
  // block-level BN reduction: LDS atomics, then one global atomic per feature
  if (half == 0) {
    int f = 4 * laneq;
    atomicAdd(&sbn[f + 0], s0);
    atomicAdd(&sbn[f + 1], s1);
    atomicAdd(&sbn[f + 2], s2);
    atomicAdd(&sbn[f + 3], s3);
    atomicAdd(&sbn[128 + f + 0], q0);
    atomicAdd(&sbn[128 + f + 1], q1);
    atomicAdd(&sbn[128 + f + 2], q2);
    atomicAdd(&sbn[128 + f + 3], q3);
  }
  __syncthreads();
  atomicAdd(&bnbuf[t], sbn[t]);
}

// ---------------------------------------------------------------- pooling (batch is sorted)
// BN coefficients for the last layer computed inline.
__global__ __launch_bounds__(256) void pool_kernel(
    const float* __restrict__ h2, const int* __restrict__ batch,
    const float* __restrict__ bnlast, const float* __restrict__ gammaL,
    const float* __restrict__ betaL,
    float* __restrict__ pool, float* __restrict__ pcnt) {
  int t = threadIdx.x;
  int lane = t & 63;
  int wid = t >> 6;
  int gw = blockIdx.x * 4 + wid;
  int nw = gridDim.x * 4;
  int chunk = (N_NODES + nw - 1) / nw;
  int n0 = gw * chunk;
  int n1 = min(n0 + chunk, N_NODES);
  if (n0 >= N_NODES) return;
  const float2* h22 = (const float2*)h2;
  int f0 = 2 * lane, f1 = f0 + 1;
  float sc0, sh0, sc1, sh1;
  bn_coeff(bnlast[f0], bnlast[128 + f0], gammaL[f0], betaL[f0], sc0, sh0);
  bn_coeff(bnlast[f1], bnlast[128 + f1], gammaL[f1], betaL[f1], sc1, sh1);
  int curg = batch[n0];
  float a0 = 0.f, a1 = 0.f, c = 0.f;
  for (int n = n0; n < n1; n++) {
    int g = batch[n];
    if (g != curg) {
      atomicAdd(&pool[curg * DIM + f0], a0);
      atomicAdd(&pool[curg * DIM + f1], a1);
      if (lane == 0) atomicAdd(&pcnt[curg], c);
      a0 = a1 = c = 0.f;
      curg = g;
    }
    float2 v = h22[(size_t)n * 64 + lane];
    a0 += fmaxf(fmaf(v.x, sc0, sh0), 0.f);
    a1 += fmaxf(fmaf(v.y, sc1, sh1), 0.f);
    c += 1.0f;
  }
  atomicAdd(&pool[curg * DIM + f0], a0);
  atomicAdd(&pool[curg * DIM + f1], a1);
  if (lane == 0) atomicAdd(&pcnt[curg], c);
}

// ---------------------------------------------------------------- output head
__global__ __launch_bounds__(256) void out_kernel(
    const float* __restrict__ pool, const float* __restrict__ pcnt,
    const float* __restrict__ Wout, const float* __restrict__ bout,
    float* __restrict__ out) {
  int idx = blockIdx.x * blockDim.x + threadIdx.x;
  if (idx >= NGRAPH * NTASK) return;
  int g = idx / NTASK, tt = idx % NTASK;
  float inv = 1.0f / fmaxf(pcnt[g], 1.0f);
  float acc = bout[tt];
  for (int d = 0; d < DIM; d++)
    acc = fmaf(pool[g * DIM + d] * inv, Wout[d * NTASK + tt], acc);
  out[idx] = acc;
}

// ----------------------------------------------------------------
extern "C" void kernel_launch(void* const* d_in, const int* in_sizes, int n_in,
                              void* d_out, int out_size, void* d_ws, size_t ws_size,
                              hipStream_t stream) {
  const float* x     = (const float*)d_in[0];
  const int*   eidx  = (const int*)d_in[1];
  const int*   row   = eidx;
  const int*   col   = eidx + N_EDGES;
  const int*   eattr = (const int*)d_in[2];
  const int*   batch = (const int*)d_in[3];
  const float* W     = (const float*)d_in[4];
  const float* b     = (const float*)d_in[5];
  const float* root  = (const float*)d_in[6];
  const float* bond  = (const float*)d_in[7];
  const float* gamma = (const float*)d_in[8];
  const float* beta  = (const float*)d_in[9];
  const float* Wout  = (const float*)d_in[10];
  const float* bout  = (const float*)d_in[11];
  float* out = (float*)d_out;

  // bump allocator over workspace
  char* w = (char*)d_ws;
  size_t off = 0;
  auto alloc = [&](size_t bytes) -> void* {
    void* p = w + off;
    off = (off + bytes + 511) & ~(size_t)511;
    return p;
  };
  // zero-init region (single memset): histograms, scatter positions, pool accumulators
  int*   cnt_row = (int*)alloc(N_NODES * 4);
  int*   cnt_col = (int*)alloc(N_NODES * 4);
  int*   pos     = (int*)alloc(N_NODES * 4);
  float* pool    = (float*)alloc(NGRAPH * DIM * 4);
  float* pcnt    = (float*)alloc(NGRAPH * 4);
  size_t zbytes  = off;
  // rest
  int*   csr     = (int*)alloc((N_NODES + 1) * 4);
  int*   bsum    = (int*)alloc(512 * 4);
  int*   bexcl   = (int*)alloc(512 * 4);
  float* deg     = (float*)alloc(N_NODES * 4);
  float* dinv    = (float*)alloc(N_NODES * 4);
  int*   spck    = (int*)alloc((size_t)N_EDGES * 4);
  float* enorm   = (float*)alloc((size_t)N_EDGES * 4);
  uint2* hxh     = (uint2*)alloc((size_t)N_NODES * DIM * 2);   // fp16 hx
  float* hA      = (float*)alloc((size_t)N_NODES * DIM * 4);
  float* hB      = (float*)alloc((size_t)N_NODES * DIM * 4);
  float* bnbufA  = (float*)alloc(256 * 4);
  float* bnbufB  = (float*)alloc(256 * 4);

  hipMemsetAsync(d_ws, 0, zbytes, stream);

  const int gblocks = (N_NODES + GBM - 1) / GBM;  // 782
  // fused: gemm layer 0 (independent of the graph) + edge histograms
  gemm0_hist_kernel<<<gblocks + 512, 512, 0, stream>>>(
      x, W, b, hxh, bnbufA, row, col, cnt_row, cnt_col, gblocks);

  const int nb = (N_NODES + 255) / 256;  // 391
  scan1_kernel<<<nb, 256, 0, stream>>>(cnt_col, csr, bsum, cnt_row, deg, dinv);
  scan2_kernel<<<1, 512, 0, stream>>>(bsum, bexcl, nb);
  scan3_kernel<<<nb, 256, 0, stream>>>(csr, bexcl);
  scatter_kernel<<<2048, 256, 0, stream>>>(row, col, eattr, csr, pos, dinv, spck, enorm);

  // layer 0 aggregation (gemm0 output already in hxh)
  agg_kernel<<<2048, 256, 0, stream>>>(
      hxh, csr, spck, enorm, bond, root, deg, hA, bnbufA);

  const float* hin = hA;
  for (int l = 1; l < NLAYER; l++) {
    float* h2      = (l % 2 == 0) ? hA : hB;
    float* bufcur  = (l % 2 == 0) ? bnbufA : bnbufB;   // this layer's partials
    float* bufprev = (l % 2 == 0) ? bnbufB : bnbufA;   // previous layer's
    gemm_kernel<<<gblocks, 512, 0, stream>>>(
        hin, W + (size_t)l * DIM * DIM, b + l * DIM,
        bufprev, gamma + (size_t)(l - 1) * DIM, beta + (size_t)(l - 1) * DIM,
        hxh, bufcur);
    agg_kernel<<<2048, 256, 0, stream>>>(
        hxh, csr, spck, enorm, bond + (size_t)l * NBOND * DIM, root + l * DIM,
        deg, h2, bufcur);
    hin = h2;
  }
  // layer 4 wrote bnbufA (4 % 2 == 0)
  pool_kernel<<<256, 256, 0, stream>>>(hin, batch, bnbufA,
                                       gamma + 4 * DIM, beta + 4 * DIM, pool, pcnt);
  out_kernel<<<5, 256, 0, stream>>>(pool, pcnt, Wout, bout, out);
}

// Round 16
// 1057.389 us; speedup vs baseline: 1.3080x; 1.1544x over previous
//
#include <hip/hip_runtime.h>
#include <hip/hip_fp16.h>
#include <math.h>

#define N_NODES 100000
#define N_EDGES 1600000
#define DIM     128
#define NLAYER  5
#define NGRAPH  128
#define NTASK   10
#define NBOND   4
#define BN_EPS  1e-5f

typedef __attribute__((ext_vector_type(8))) _Float16 half8;
typedef __attribute__((ext_vector_type(4))) float f32x4;

// ---------------------------------------------------------------- scan (CSR offsets) + deg
__global__ __launch_bounds__(256) void scan1_kernel(
    const int* __restrict__ cnt, int* __restrict__ excl, int* __restrict__ bsum,
    const int* __restrict__ cnt_row, float* __restrict__ deg, float* __restrict__ dinv) {
  __shared__ int s[256];
  int t = threadIdx.x;
  int i = blockIdx.x * 256 + t;
  if (i < N_NODES) {
    float d = (float)cnt_row[i] + 1.0f;
    deg[i] = d;
    dinv[i] = rsqrtf(d);
  }
  int v = (i < N_NODES) ? cnt[i] : 0;
  s[t] = v;
  __syncthreads();
  for (int off = 1; off < 256; off <<= 1) {
    int add = (t >= off) ? s[t - off] : 0;
    __syncthreads();
    s[t] += add;
    __syncthreads();
  }
  if (i < N_NODES) excl[i] = s[t] - v;   // exclusive within block
  if (t == 255) bsum[blockIdx.x] = s[255];
}

__global__ __launch_bounds__(512) void scan2_kernel(
    const int* __restrict__ bsum, int* __restrict__ bexcl, int nb) {
  __shared__ int s[512];
  int t = threadIdx.x;
  int v = (t < nb) ? bsum[t] : 0;
  s[t] = v;
  __syncthreads();
  for (int off = 1; off < 512; off <<= 1) {
    int add = (t >= off) ? s[t - off] : 0;
    __syncthreads();
    s[t] += add;
    __syncthreads();
  }
  if (t < nb) bexcl[t] = s[t] - v;
}

__global__ __launch_bounds__(256) void scan3_kernel(
    int* __restrict__ excl, const int* __restrict__ bexcl) {
  int i = blockIdx.x * 256 + threadIdx.x;
  if (i < N_NODES) excl[i] += bexcl[blockIdx.x];
  if (i == 0) excl[N_NODES] = N_EDGES;
}

// ---------------------------------------------------------------- CSR scatter
__global__ __launch_bounds__(256) void scatter_kernel(
    const int* __restrict__ row, const int* __restrict__ col,
    const int* __restrict__ attr, const int* __restrict__ csr_off,
    int* __restrict__ pos, const float* __restrict__ dinv,
    int* __restrict__ src_pack, float* __restrict__ enorm) {
  int e = blockIdx.x * blockDim.x + threadIdx.x;
  int stride = gridDim.x * blockDim.x;
  for (; e < N_EDGES; e += stride) {
    int d = col[e];
    int s = row[e];
    int p = csr_off[d] + atomicAdd(&pos[d], 1);
    src_pack[p] = s | (attr[e] << 20);         // src < 2^20, attr < 4
    enorm[p] = dinv[s] * dinv[d];
  }
}

// ---------------------------------------------------------------- BN coeff helper
__device__ __forceinline__ void bn_coeff(float s, float q, float g, float b,
                                         float& sc, float& sh) {
  const float invN = 1.0f / (float)N_NODES;
  float mu = s * invN;
  float ex2 = q * invN;
  float var = ex2 - mu * mu;
  float inv = rsqrtf(var + BN_EPS);
  sc = g * inv;
  sh = fmaf(-mu, sc, b);
}

// ---------------------------------------------------------------- W -> fp16 fragment layout
// W16[(layer*32 + kb*8 + ct)*64 + lane] holds the 8 halves lane needs for the
// MFMA B-operand of K-step kb, col-tile ct:  B[k][col], col = ct*16+(lane&15),
// k = kb*32 + (lane>>4)*8 + e.  One 16B store per lane; gemm reads it back as
// one 16B L2-hot load per (kb, ct).
__global__ __launch_bounds__(256) void wcvt_kernel(
    const float* __restrict__ W, uint4* __restrict__ W16) {
  int g = (blockIdx.x * 256 + threadIdx.x) >> 6;   // wave id 0..159
  int lane = threadIdx.x & 63;
  if (g >= NLAYER * 32) return;
  int layer = g >> 5;
  int rem = g & 31;
  int kb = rem >> 3, ct = rem & 7;
  const float* Wl = W + (size_t)layer * DIM * DIM;
  int c = ct * 16 + (lane & 15);
  int kbase = kb * 32 + (lane >> 4) * 8;
  __half h[8];
#pragma unroll
  for (int e = 0; e < 8; e++)
    h[e] = __float2half_rn(Wl[(size_t)(kbase + e) * DIM + c]);
  uint4 u;
  u.x = __builtin_bit_cast(unsigned int, __halves2half2(h[0], h[1]));
  u.y = __builtin_bit_cast(unsigned int, __halves2half2(h[2], h[3]));
  u.z = __builtin_bit_cast(unsigned int, __halves2half2(h[4], h[5]));
  u.w = __builtin_bit_cast(unsigned int, __halves2half2(h[6], h[7]));
  W16[(size_t)g * 64 + lane] = u;
}

// ---------------------------------------------------------------- MFMA GEMM body
// R16: gemm moves to the matrix pipe (R5-R9: four vector-ALU schedules all
// converged at ~88us = 4x the VALU floor; MfmaUtil was 0.0 all session).
// Block = 256 threads = 4 waves; 64-row x 128-col output tile.
// - act(h) staged once as fp16 in LDS: 64 rows x 16 slots x 16B, slot
//   XOR-swizzled by row&7 -> 2-way conflict (free).
// - W read from the pre-converted fragment-ordered fp16 buffer (L2-hot).
// - wave w owns rows w*16..w*16+15; 8 col-tiles x 4 K-steps of
//   mfma_f32_16x16x32_f16, fp32 acc init = bias.
// Fragment layouts (guide §3): A row=lane&15, k=(lane>>4)*8+e; B col=lane&15,
// same k; C/D col=lane&15, row=(lane>>4)*4+reg (m89-verified).
#define GBM 64
template<int USEACT>
__device__ __forceinline__ void gemm_body(
    const float* __restrict__ hin, const uint4* __restrict__ W16,
    const float* __restrict__ bias, const float* __restrict__ bnprev,
    const float* __restrict__ gammaL, const float* __restrict__ betaL,
    __half* __restrict__ hxh, uint4* As, float* scS, float* shS, int bid) {
  int t = threadIdx.x;
  int lane = t & 63, w = t >> 6;
  if (USEACT) {
    if (t < 128) {
      float sc, sh;
      bn_coeff(bnprev[t], bnprev[128 + t], gammaL[t], betaL[t], sc, sh);
      scS[t] = sc; shS[t] = sh;
    }
    __syncthreads();
  }
  int r0 = bid * GBM;
  if (r0 > N_NODES - GBM) r0 = N_NODES - GBM;   // tail overlap (identical dup stores)

  // ---- stage act(h) as fp16 into LDS
  const float4* hg = (const float4*)hin;
  int srow = t >> 2;                    // 0..63
#pragma unroll
  for (int i = 0; i < 4; i++) {
    int s = (t & 3) + 4 * i;            // slot 0..15 (8 k-values each)
    float4 a = hg[(size_t)(r0 + srow) * 32 + 2 * s];
    float4 b = hg[(size_t)(r0 + srow) * 32 + 2 * s + 1];
    if (USEACT) {
      int k = s * 8;
      a.x = fmaxf(fmaf(a.x, scS[k],     shS[k]),     0.f);
      a.y = fmaxf(fmaf(a.y, scS[k + 1], shS[k + 1]), 0.f);
      a.z = fmaxf(fmaf(a.z, scS[k + 2], shS[k + 2]), 0.f);
      a.w = fmaxf(fmaf(a.w, scS[k + 3], shS[k + 3]), 0.f);
      b.x = fmaxf(fmaf(b.x, scS[k + 4], shS[k + 4]), 0.f);
      b.y = fmaxf(fmaf(b.y, scS[k + 5], shS[k + 5]), 0.f);
      b.z = fmaxf(fmaf(b.z, scS[k + 6], shS[k + 6]), 0.f);
      b.w = fmaxf(fmaf(b.w, scS[k + 7], shS[k + 7]), 0.f);
    }
    uint4 u;
    u.x = __builtin_bit_cast(unsigned int, __floats2half2_rn(a.x, a.y));
    u.y = __builtin_bit_cast(unsigned int, __floats2half2_rn(a.z, a.w));
    u.z = __builtin_bit_cast(unsigned int, __floats2half2_rn(b.x, b.y));
    u.w = __builtin_bit_cast(unsigned int, __floats2half2_rn(b.z, b.w));
    As[srow * 16 + (s ^ (srow & 7))] = u;
  }
  __syncthreads();

  // ---- accumulators init = bias (C/D col = lane&15)
  f32x4 acc[8];
#pragma unroll
  for (int ct = 0; ct < 8; ct++) {
    float bv = bias[ct * 16 + (lane & 15)];
    f32x4 v; v[0] = bv; v[1] = bv; v[2] = bv; v[3] = bv;
    acc[ct] = v;
  }

  // ---- K loop: 4 steps of K=32
  int rl = w * 16 + (lane & 15);        // A row (local)
#pragma unroll
  for (int kb = 0; kb < 4; kb++) {
    int s = kb * 4 + (lane >> 4);
    half8 af = __builtin_bit_cast(half8, As[rl * 16 + (s ^ (rl & 7))]);
#pragma unroll
    for (int ct = 0; ct < 8; ct++) {
      half8 bf = __builtin_bit_cast(half8, W16[(kb * 8 + ct) * 64 + lane]);
      acc[ct] = __builtin_amdgcn_mfma_f32_16x16x32_f16(af, bf, acc[ct], 0, 0, 0);
    }
  }

  // ---- store C as fp16: col = ct*16+(lane&15), row = w*16+(lane>>4)*4+reg
  int colb = lane & 15;
  int rowb = r0 + w * 16 + (lane >> 4) * 4;
#pragma unroll
  for (int ct = 0; ct < 8; ct++) {
#pragma unroll
    for (int reg = 0; reg < 4; reg++) {
      hxh[(size_t)(rowb + reg) * 128 + ct * 16 + colb] = __float2half_rn(acc[ct][reg]);
    }
  }
}

// ---------------------------------------------------------------- gemm layers 1-4
__global__ __launch_bounds__(256) void gemm_kernel(
    const float* __restrict__ hin, const uint4* __restrict__ W16,
    const float* __restrict__ bias, const float* __restrict__ bnprev,
    const float* __restrict__ gammaL, const float* __restrict__ betaL,
    __half* __restrict__ hxh, float* __restrict__ bnzero) {
  __shared__ uint4 As[64 * 16];
  __shared__ float scS[DIM], shS[DIM];
  if (blockIdx.x == 0) bnzero[threadIdx.x] = 0.0f;
  gemm_body<1>(hin, W16, bias, bnprev, gammaL, betaL, hxh, As, scS, shS, blockIdx.x);
}

// ---------------------------------------------------------------- gemm layer 0 + edge histograms (fused)
__global__ __launch_bounds__(256) void gemm0_hist_kernel(
    const float* __restrict__ x, const uint4* __restrict__ W16,
    const float* __restrict__ bias, __half* __restrict__ hxh,
    float* __restrict__ bnzero,
    const int* __restrict__ row, const int* __restrict__ col,
    int* __restrict__ cnt_row, int* __restrict__ cnt_col, int gblocks) {
  __shared__ uint4 As[64 * 16];
  __shared__ float scS[DIM], shS[DIM];
  int t = threadIdx.x;
  if ((int)blockIdx.x >= gblocks) {     // histogram branch (block-uniform)
    int i = ((int)blockIdx.x - gblocks) * 256 + t;
    int stride = ((int)gridDim.x - gblocks) * 256;
    for (; i < N_EDGES; i += stride) {
      atomicAdd(&cnt_row[row[i]], 1);
      atomicAdd(&cnt_col[col[i]], 1);
    }
    return;
  }
  if (blockIdx.x == 0) bnzero[t] = 0.0f;
  gemm_body<0>(x, W16, bias, nullptr, nullptr, nullptr, hxh, As, scS, shS, blockIdx.x);
}

// ---------------------------------------------------------------- edge aggregation
// R13/R15-verified structure: 4-deep gather pipeline (measured optimum:
// 2->4 helped at fp32 rows, 4->8 hurt at fp16 rows), separate src_pack/enorm
// streams, fp16 hx rows (256B). BN partials: LDS block reduce -> one global
// atomic per feature.
__global__ __launch_bounds__(256) void agg_kernel(
    const uint2* __restrict__ hxh, const int* __restrict__ csr_off,
    const int* __restrict__ src_pack, const float* __restrict__ enorm,
    const float* __restrict__ bond, const float* __restrict__ root,
    const float* __restrict__ deg, float* __restrict__ h2,
    float* __restrict__ bnbuf) {
  __shared__ float4 bondS[NBOND * 32];
  __shared__ float4 rootS[32];
  __shared__ float sbn[256];
  int t = threadIdx.x;
  if (t < NBOND * 32) bondS[t] = ((const float4*)bond)[t];
  if (t < 32) rootS[t] = ((const float4*)root)[t];
  sbn[t] = 0.0f;
  __syncthreads();

  int lane = t & 63;
  int laneq = lane & 31;   // feature quad owner
  int half = lane >> 5;    // which edge stream of the pair
  int wid = t >> 6;
  int gw = blockIdx.x * 4 + wid;
  int nw = gridDim.x * 4;
  float4* h24 = (float4*)h2;

  float s0 = 0.f, s1 = 0.f, s2 = 0.f, s3 = 0.f;
  float q0 = 0.f, q1 = 0.f, q2 = 0.f, q3 = 0.f;
  for (int n = gw; n < N_NODES; n += nw) {
    int e0 = csr_off[n], e1 = csr_off[n + 1];
    float a0 = 0.f, a1 = 0.f, a2 = 0.f, a3 = 0.f;
    int e = e0 + half;
    for (; e + 6 < e1; e += 8) {
      int sp0 = src_pack[e];
      int sp1 = src_pack[e + 2];
      int sp2 = src_pack[e + 4];
      int sp3 = src_pack[e + 6];
      float nr0 = enorm[e];
      float nr1 = enorm[e + 2];
      float nr2 = enorm[e + 4];
      float nr3 = enorm[e + 6];
      uint2 u0 = hxh[(size_t)(sp0 & 0xFFFFF) * 32 + laneq];
      uint2 u1 = hxh[(size_t)(sp1 & 0xFFFFF) * 32 + laneq];
      uint2 u2 = hxh[(size_t)(sp2 & 0xFFFFF) * 32 + laneq];
      uint2 u3 = hxh[(size_t)(sp3 & 0xFFFFF) * 32 + laneq];
      float4 b0 = bondS[(sp0 >> 20) * 32 + laneq];
      float4 b1 = bondS[(sp1 >> 20) * 32 + laneq];
      float4 b2 = bondS[(sp2 >> 20) * 32 + laneq];
      float4 b3 = bondS[(sp3 >> 20) * 32 + laneq];
      float2 v0a = __half22float2(__builtin_bit_cast(__half2, u0.x));
      float2 v0b = __half22float2(__builtin_bit_cast(__half2, u0.y));
      float2 v1a = __half22float2(__builtin_bit_cast(__half2, u1.x));
      float2 v1b = __half22float2(__builtin_bit_cast(__half2, u1.y));
      float2 v2a = __half22float2(__builtin_bit_cast(__half2, u2.x));
      float2 v2b = __half22float2(__builtin_bit_cast(__half2, u2.y));
      float2 v3a = __half22float2(__builtin_bit_cast(__half2, u3.x));
      float2 v3b = __half22float2(__builtin_bit_cast(__half2, u3.y));
      a0 = fmaf(nr0, fmaxf(v0a.x + b0.x, 0.f), a0);
      a1 = fmaf(nr0, fmaxf(v0a.y + b0.y, 0.f), a1);
      a2 = fmaf(nr0, fmaxf(v0b.x + b0.z, 0.f), a2);
      a3 = fmaf(nr0, fmaxf(v0b.y + b0.w, 0.f), a3);
      a0 = fmaf(nr1, fmaxf(v1a.x + b1.x, 0.f), a0);
      a1 = fmaf(nr1, fmaxf(v1a.y + b1.y, 0.f), a1);
      a2 = fmaf(nr1, fmaxf(v1b.x + b1.z, 0.f), a2);
      a3 = fmaf(nr1, fmaxf(v1b.y + b1.w, 0.f), a3);
      a0 = fmaf(nr2, fmaxf(v2a.x + b2.x, 0.f), a0);
      a1 = fmaf(nr2, fmaxf(v2a.y + b2.y, 0.f), a1);
      a2 = fmaf(nr2, fmaxf(v2b.x + b2.z, 0.f), a2);
      a3 = fmaf(nr2, fmaxf(v2b.y + b2.w, 0.f), a3);
      a0 = fmaf(nr3, fmaxf(v3a.x + b3.x, 0.f), a0);
      a1 = fmaf(nr3, fmaxf(v3a.y + b3.y, 0.f), a1);
      a2 = fmaf(nr3, fmaxf(v3b.x + b3.z, 0.f), a2);
      a3 = fmaf(nr3, fmaxf(v3b.y + b3.w, 0.f), a3);
    }
    for (; e < e1; e += 2) {
      int sp = src_pack[e];
      float nrm = enorm[e];
      uint2 u = hxh[(size_t)(sp & 0xFFFFF) * 32 + laneq];
      float4 eb = bondS[(sp >> 20) * 32 + laneq];
      float2 va = __half22float2(__builtin_bit_cast(__half2, u.x));
      float2 vb = __half22float2(__builtin_bit_cast(__half2, u.y));
      a0 = fmaf(nrm, fmaxf(va.x + eb.x, 0.f), a0);
      a1 = fmaf(nrm, fmaxf(va.y + eb.y, 0.f), a1);
      a2 = fmaf(nrm, fmaxf(vb.x + eb.z, 0.f), a2);
      a3 = fmaf(nrm, fmaxf(vb.y + eb.w, 0.f), a3);
    }
    a0 += __shfl_xor(a0, 32, 64);
    a1 += __shfl_xor(a1, 32, 64);
    a2 += __shfl_xor(a2, 32, 64);
    a3 += __shfl_xor(a3, 32, 64);
    if (half == 0) {
      float inv = 1.0f / deg[n];
      uint2 u = hxh[(size_t)n * 32 + laneq];
      float2 va = __half22float2(__builtin_bit_cast(__half2, u.x));
      float2 vb = __half22float2(__builtin_bit_cast(__half2, u.y));
      float4 r = rootS[laneq];
      a0 += fmaxf(va.x + r.x, 0.f) * inv;
      a1 += fmaxf(va.y + r.y, 0.f) * inv;
      a2 += fmaxf(vb.x + r.z, 0.f) * inv;
      a3 += fmaxf(vb.y + r.w, 0.f) * inv;
      float4 o;
      o.x = a0; o.y = a1; o.z = a2; o.w = a3;
      h24[(size_t)n * 32 + laneq] = o;
      s0 += a0; s1 += a1; s2 += a2; s3 += a3;
      q0 += a0 * a0; q1 += a1 * a1; q2 += a2 * a2; q3 += a3 * a3;
    }
  }
  if (half == 0) {
    int f = 4 * laneq;
    atomicAdd(&sbn[f + 0], s0);
    atomicAdd(&sbn[f + 1], s1);
    atomicAdd(&sbn[f + 2], s2);
    atomicAdd(&sbn[f + 3], s3);
    atomicAdd(&sbn[128 + f + 0], q0);
    atomicAdd(&sbn[128 + f + 1], q1);
    atomicAdd(&sbn[128 + f + 2], q2);
    atomicAdd(&sbn[128 + f + 3], q3);
  }
  __syncthreads();
  atomicAdd(&bnbuf[t], sbn[t]);
}

// ---------------------------------------------------------------- pooling (batch is sorted)
__global__ __launch_bounds__(256) void pool_kernel(
    const float* __restrict__ h2, const int* __restrict__ batch,
    const float* __restrict__ bnlast, const float* __restrict__ gammaL,
    const float* __restrict__ betaL,
    float* __restrict__ pool, float* __restrict__ pcnt) {
  int t = threadIdx.x;
  int lane = t & 63;
  int wid = t >> 6;
  int gw = blockIdx.x * 4 + wid;
  int nw = gridDim.x * 4;
  int chunk = (N_NODES + nw - 1) / nw;
  int n0 = gw * chunk;
  int n1 = min(n0 + chunk, N_NODES);
  if (n0 >= N_NODES) return;
  const float2* h22 = (const float2*)h2;
  int f0 = 2 * lane, f1 = f0 + 1;
  float sc0, sh0, sc1, sh1;
  bn_coeff(bnlast[f0], bnlast[128 + f0], gammaL[f0], betaL[f0], sc0, sh0);
  bn_coeff(bnlast[f1], bnlast[128 + f1], gammaL[f1], betaL[f1], sc1, sh1);
  int curg = batch[n0];
  float a0 = 0.f, a1 = 0.f, c = 0.f;
  for (int n = n0; n < n1; n++) {
    int g = batch[n];
    if (g != curg) {
      atomicAdd(&pool[curg * DIM + f0], a0);
      atomicAdd(&pool[curg * DIM + f1], a1);
      if (lane == 0) atomicAdd(&pcnt[curg], c);
      a0 = a1 = c = 0.f;
      curg = g;
    }
    float2 v = h22[(size_t)n * 64 + lane];
    a0 += fmaxf(fmaf(v.x, sc0, sh0), 0.f);
    a1 += fmaxf(fmaf(v.y, sc1, sh1), 0.f);
    c += 1.0f;
  }
  atomicAdd(&pool[curg * DIM + f0], a0);
  atomicAdd(&pool[curg * DIM + f1], a1);
  if (lane == 0) atomicAdd(&pcnt[curg], c);
}

// ---------------------------------------------------------------- output head
__global__ __launch_bounds__(256) void out_kernel(
    const float* __restrict__ pool, const float* __restrict__ pcnt,
    const float* __restrict__ Wout, const float* __restrict__ bout,
    float* __restrict__ out) {
  int idx = blockIdx.x * blockDim.x + threadIdx.x;
  if (idx >= NGRAPH * NTASK) return;
  int g = idx / NTASK, tt = idx % NTASK;
  float inv = 1.0f / fmaxf(pcnt[g], 1.0f);
  float acc = bout[tt];
  for (int d = 0; d < DIM; d++)
    acc = fmaf(pool[g * DIM + d] * inv, Wout[d * NTASK + tt], acc);
  out[idx] = acc;
}

// ----------------------------------------------------------------
extern "C" void kernel_launch(void* const* d_in, const int* in_sizes, int n_in,
                              void* d_out, int out_size, void* d_ws, size_t ws_size,
                              hipStream_t stream) {
  const float* x     = (const float*)d_in[0];
  const int*   eidx  = (const int*)d_in[1];
  const int*   row   = eidx;
  const int*   col   = eidx + N_EDGES;
  const int*   eattr = (const int*)d_in[2];
  const int*   batch = (const int*)d_in[3];
  const float* W     = (const float*)d_in[4];
  const float* b     = (const float*)d_in[5];
  const float* root  = (const float*)d_in[6];
  const float* bond  = (const float*)d_in[7];
  const float* gamma = (const float*)d_in[8];
  const float* beta  = (const float*)d_in[9];
  const float* Wout  = (const float*)d_in[10];
  const float* bout  = (const float*)d_in[11];
  float* out = (float*)d_out;

  // bump allocator over workspace
  char* w = (char*)d_ws;
  size_t off = 0;
  auto alloc = [&](size_t bytes) -> void* {
    void* p = w + off;
    off = (off + bytes + 511) & ~(size_t)511;
    return p;
  };
  // zero-init region (single memset): histograms, scatter positions, pool accumulators
  int*   cnt_row = (int*)alloc(N_NODES * 4);
  int*   cnt_col = (int*)alloc(N_NODES * 4);
  int*   pos     = (int*)alloc(N_NODES * 4);
  float* pool    = (float*)alloc(NGRAPH * DIM * 4);
  float* pcnt    = (float*)alloc(NGRAPH * 4);
  size_t zbytes  = off;
  // rest
  int*   csr     = (int*)alloc((N_NODES + 1) * 4);
  int*   bsum    = (int*)alloc(512 * 4);
  int*   bexcl   = (int*)alloc(512 * 4);
  float* deg     = (float*)alloc(N_NODES * 4);
  float* dinv    = (float*)alloc(N_NODES * 4);
  int*   spck    = (int*)alloc((size_t)N_EDGES * 4);
  float* enorm   = (float*)alloc((size_t)N_EDGES * 4);
  uint2* hxh     = (uint2*)alloc((size_t)N_NODES * DIM * 2);   // fp16 hx
  float* hA      = (float*)alloc((size_t)N_NODES * DIM * 4);
  float* hB      = (float*)alloc((size_t)N_NODES * DIM * 4);
  uint4* W16     = (uint4*)alloc((size_t)NLAYER * 2048 * 16);  // fp16 W, frag order
  float* bnbufA  = (float*)alloc(256 * 4);
  float* bnbufB  = (float*)alloc(256 * 4);

  hipMemsetAsync(d_ws, 0, zbytes, stream);

  // convert all W layers to fp16 fragment layout (gemm0 depends on layer 0)
  wcvt_kernel<<<40, 256, 0, stream>>>(W, W16);

  const int gblocks = (N_NODES + GBM - 1) / GBM;  // 1563
  // fused: gemm layer 0 (independent of the graph) + edge histograms
  gemm0_hist_kernel<<<gblocks + 1024, 256, 0, stream>>>(
      x, W16, b, (__half*)hxh, bnbufA, row, col, cnt_row, cnt_col, gblocks);

  const int nb = (N_NODES + 255) / 256;  // 391
  scan1_kernel<<<nb, 256, 0, stream>>>(cnt_col, csr, bsum, cnt_row, deg, dinv);
  scan2_kernel<<<1, 512, 0, stream>>>(bsum, bexcl, nb);
  scan3_kernel<<<nb, 256, 0, stream>>>(csr, bexcl);
  scatter_kernel<<<2048, 256, 0, stream>>>(row, col, eattr, csr, pos, dinv, spck, enorm);

  // layer 0 aggregation (gemm0 output already in hxh)
  agg_kernel<<<2048, 256, 0, stream>>>(
      hxh, csr, spck, enorm, bond, root, deg, hA, bnbufA);

  const float* hin = hA;
  for (int l = 1; l < NLAYER; l++) {
    float* h2      = (l % 2 == 0) ? hA : hB;
    float* bufcur  = (l % 2 == 0) ? bnbufA : bnbufB;   // this layer's partials
    float* bufprev = (l % 2 == 0) ? bnbufB : bnbufA;   // previous layer's
    gemm_kernel<<<gblocks, 256, 0, stream>>>(
        hin, W16 + (size_t)l * 2048, b + l * DIM,
        bufprev, gamma + (size_t)(l - 1) * DIM, beta + (size_t)(l - 1) * DIM,
        (__half*)hxh, bufcur);
    agg_kernel<<<2048, 256, 0, stream>>>(
        hxh, csr, spck, enorm, bond + (size_t)l * NBOND * DIM, root + l * DIM,
        deg, h2, bufcur);
    hin = h2;
  }
  // layer 4 wrote bnbufA (4 % 2 == 0)
  pool_kernel<<<256, 256, 0, stream>>>(hin, batch, bnbufA,
                                       gamma + 4 * DIM, beta + 4 * DIM, pool, pcnt);
  out_kernel<<<5, 256, 0, stream>>>(pool, pcnt, Wout, bout, out);
}